// Round 1
// baseline (256.966 us; speedup 1.0000x reference)
//
#include <hip/hip_runtime.h>
#include <hip/hip_bf16.h>

#define M_DIM 4096
#define N_DIM 4096
#define K_DIM 4096
#define BM 128
#define BN 128
#define BK 32
#define NT (K_DIM / BK)
#define LDS_STRIDE 40  // 32 + 8 pad (bf16 elems) -> breaks bank-conflict stride

typedef __attribute__((ext_vector_type(8))) short short8;
typedef __attribute__((ext_vector_type(4))) float float4v;

__device__ __forceinline__ unsigned short f2bf(float f) {
    return __builtin_bit_cast(unsigned short, __float2bfloat16(f));
}

__global__ __launch_bounds__(256, 2)
void gemm_xwt_bias(const float* __restrict__ X, const float* __restrict__ W,
                   const float* __restrict__ Bv, float* __restrict__ O) {
    __shared__ __align__(16) unsigned short lds_a[2][BM * LDS_STRIDE];
    __shared__ __align__(16) unsigned short lds_b[2][BN * LDS_STRIDE];

    const int tid  = threadIdx.x;
    const int lane = tid & 63;
    const int wid  = tid >> 6;
    const int wr   = wid >> 1;   // wave row (0..1)
    const int wc   = wid & 1;    // wave col (0..1)
    const int brow = blockIdx.y * BM;
    const int bcol = blockIdx.x * BN;

    // staging: thread t owns row (t>>1), 16-float half (t&1) of the 128x32 tile
    const int srow  = tid >> 1;
    const int shalf = (tid & 1) * 16;

    const float* gA = X + (long)(brow + srow) * K_DIM + shalf;
    const float* gB = W + (long)(bcol + srow) * K_DIM + shalf;

    float4v ra[4], rb[4];

    auto load_regs = [&](int kt) {
        const float* pa = gA + kt * BK;
        const float* pb = gB + kt * BK;
#pragma unroll
        for (int j = 0; j < 4; ++j) ra[j] = *(const float4v*)(pa + j * 4);
#pragma unroll
        for (int j = 0; j < 4; ++j) rb[j] = *(const float4v*)(pb + j * 4);
    };

    auto write_lds = [&](int buf) {
        unsigned short* da = &lds_a[buf][srow * LDS_STRIDE + shalf];
        unsigned short* db = &lds_b[buf][srow * LDS_STRIDE + shalf];
        short8 va0, va1, vb0, vb1;
#pragma unroll
        for (int e = 0; e < 4; ++e) {
            va0[e]     = (short)f2bf(ra[0][e]);
            va0[e + 4] = (short)f2bf(ra[1][e]);
            va1[e]     = (short)f2bf(ra[2][e]);
            va1[e + 4] = (short)f2bf(ra[3][e]);
            vb0[e]     = (short)f2bf(rb[0][e]);
            vb0[e + 4] = (short)f2bf(rb[1][e]);
            vb1[e]     = (short)f2bf(rb[2][e]);
            vb1[e + 4] = (short)f2bf(rb[3][e]);
        }
        *(short8*)(da)     = va0;
        *(short8*)(da + 8) = va1;
        *(short8*)(db)     = vb0;
        *(short8*)(db + 8) = vb1;
    };

    float4v acc[4][4] = {};

    load_regs(0);
    write_lds(0);
    load_regs(1);
    __syncthreads();

    for (int kt = 0; kt < NT; ++kt) {
        const int cur = kt & 1;
        if (kt + 1 < NT) write_lds(cur ^ 1);   // regs hold kt+1's data
        if (kt + 2 < NT) load_regs(kt + 2);    // issue loads; in flight across barrier

        // LDS -> register fragments (8x ds_read_b128)
        const unsigned short* ba =
            &lds_a[cur][(wr * 64 + (lane & 15)) * LDS_STRIDE + (lane >> 4) * 8];
        const unsigned short* bb =
            &lds_b[cur][(wc * 64 + (lane & 15)) * LDS_STRIDE + (lane >> 4) * 8];
        short8 af[4], bfr[4];
#pragma unroll
        for (int i = 0; i < 4; ++i) {
            af[i]  = *(const short8*)(ba + i * 16 * LDS_STRIDE);
            bfr[i] = *(const short8*)(bb + i * 16 * LDS_STRIDE);
        }

#pragma unroll
        for (int mi = 0; mi < 4; ++mi)
#pragma unroll
            for (int ni = 0; ni < 4; ++ni)
                acc[mi][ni] = __builtin_amdgcn_mfma_f32_16x16x32_bf16(
                    af[mi], bfr[ni], acc[mi][ni], 0, 0, 0);

        __syncthreads();
    }

    // epilogue: D lane layout col = lane&15, row = (lane>>4)*4 + r
#pragma unroll
    for (int ni = 0; ni < 4; ++ni) {
        const int col = bcol + wc * 64 + ni * 16 + (lane & 15);
        const float bias = Bv[col];
#pragma unroll
        for (int mi = 0; mi < 4; ++mi) {
            const int row0 = brow + wr * 64 + mi * 16 + (lane >> 4) * 4;
#pragma unroll
            for (int r = 0; r < 4; ++r)
                O[(long)(row0 + r) * N_DIM + col] = acc[mi][ni][r] + bias;
        }
    }
}

extern "C" void kernel_launch(void* const* d_in, const int* in_sizes, int n_in,
                              void* d_out, int out_size, void* d_ws, size_t ws_size,
                              hipStream_t stream) {
    const float* X  = (const float*)d_in[0];
    const float* W  = (const float*)d_in[1];
    const float* Bv = (const float*)d_in[2];
    float* O        = (float*)d_out;

    dim3 grid(N_DIM / BN, M_DIM / BM);
    dim3 block(256);
    hipLaunchKernelGGL(gemm_xwt_bias, grid, block, 0, stream, X, W, Bv, O);
}